// Round 16
// baseline (269.431 us; speedup 1.0000x reference)
//
#include <hip/hip_runtime.h>

#define NT   512
#define IMPN (2048 * 512)

typedef __attribute__((ext_vector_type(8))) short short8v;
typedef __attribute__((ext_vector_type(4))) float f32x4;
typedef __attribute__((ext_vector_type(2))) float f32x2;

union Frag { short8v v; unsigned short s[8]; };

#define L2E 1.4426950408889634f

// bare v_exp_f32 (2^x): 1 instruction (libm exp2f costs ~10+ VALU, R10).
__device__ __forceinline__ float fexp2(float x) {
    float r;
    asm("v_exp_f32 %0, %1" : "=v"(r) : "v"(x));
    return r;
}
__device__ __forceinline__ unsigned short f2bf(float f) {
    unsigned u = __float_as_uint(f);
    unsigned r = u + 0x7FFFu + ((u >> 16) & 1u);
    return (unsigned short)(r >> 16);
}
__device__ __forceinline__ float bf2f(unsigned short s) {
    return __uint_as_float(((unsigned)s) << 16);
}
__device__ __forceinline__ unsigned cvt_pk_bf16(float a, float b) {
    unsigned r;
    asm("v_cvt_pk_bf16_f32 %0, %1, %2" : "=v"(r) : "v"(a), "v"(b));
    return r;
}
// packed sigmoid tail: rcp(1 + exp2(arg)) per component
__device__ __forceinline__ f32x2 fsig2v(f32x2 arg) {
    f32x2 e;
    e.x = fexp2(arg.x);
    e.y = fexp2(arg.y);
    e += (f32x2){1.0f, 1.0f};
    f32x2 s;
    s.x = __builtin_amdgcn_rcpf(e.x);
    s.y = __builtin_amdgcn_rcpf(e.y);
    return s;
}

// 256 blocks x 256 threads, 1 block/CU (1024 full-lane waves = 1 wave/SIMD
// chip-wide; R6/R8: multi-stream variants waste lanes or idle CUs; R9: serial
// cross-lane latency > MFMA issue cost; R10/R11: bare v_exp_f32 only;
// R12: single-level h holds precision; R13: keep dependent gate math AFTER
// the MFMAs; R14: f32x2 q-pair packing; R15: XOR-swizzled h_lds).
// Blocks 0..127 fwd, 128..255 bwd; block = 16 seqs. TRANSPOSED MFMA
// (weights = A, h = B): D[gate-row][seq], lane (j,g) owns seq j, units
// 16w+4g+{0..3}. 8 MFMA/step: r,z,n = W_H*h_H (6) + xh = rW_H*h_H (2).
// R16a: next-step decay FUSED into phase C (dsg computed in phase B from
// xmd_nxt, independent of MFMA -> fills MFMA shadow; applied to the h update).
// Top-of-step = pack+write only. Chunk-boundary steps (stale xmd_nxt) take an
// explicit decay path; dsg=1 at tm==31 keeps phase C branchless.
// R16b: gate args reassociated around xh: arg = (acc + C) + Q*xh with
// C = wx*xcA + wm*mv + b, Q = wx*xcB precomputed in phase B (post-MFMA-issue).
// NEGATED exp2 PRESCALING: r/z x(-log2e), n x(-2log2e), decay x(-log2e);
// rW/acc3 natural. dir=1 consumes time REVERSED; imp stored at scan index.
__global__ __launch_bounds__(256, 1) void brits_mfma(
    const float* __restrict__ input,
    const float* __restrict__ gW_f, const float* __restrict__ gb_f,
    const float* __restrict__ rW_f, const float* __restrict__ rb_f,
    const float* __restrict__ fcW_f, const float* __restrict__ fcb_f,
    const float* __restrict__ Wih_f, const float* __restrict__ bih_f,
    const float* __restrict__ Whh_f, const float* __restrict__ bhh_f,
    const float* __restrict__ gW_b, const float* __restrict__ gb_b,
    const float* __restrict__ rW_b, const float* __restrict__ rb_b,
    const float* __restrict__ fcW_b, const float* __restrict__ fcb_b,
    const float* __restrict__ Wih_b, const float* __restrict__ bih_b,
    const float* __restrict__ Whh_b, const float* __restrict__ bhh_b,
    float* __restrict__ out, float* __restrict__ ws)
{
    __shared__ __align__(16) unsigned short h_lds[2][16 * 64];   // [buf][seq*64+swz-unit]
    __shared__ __align__(16) float xmd_l[16][33][4];             // [seq][tau(+pad)][x,m,d,-]
    __shared__ __align__(16) float impbuf[16][33];
    __shared__ __align__(16) float fcpart[16][4];

    const int tid  = threadIdx.x;
    const int w    = tid >> 6;
    const int lane = tid & 63;
    const int j    = lane & 15;          // seq owned by this lane
    const int g    = lane >> 4;
    const int u    = w * 16 + j;         // weight-frag row unit
    const int u0   = w * 16 + 4 * g;     // first of this lane's 4 gate units
    const int dir  = blockIdx.x >> 7;
    const int b0   = (blockIdx.x & 127) * 16;

    const float* gW  = dir ? gW_b  : gW_f;
    const float* gb  = dir ? gb_b  : gb_f;
    const float* rW  = dir ? rW_b  : rW_f;
    const float* rb  = dir ? rb_b  : rb_f;
    const float* fcW = dir ? fcW_b : fcW_f;
    const float* fcb = dir ? fcb_b : fcb_f;
    const float* Wih = dir ? Wih_b : Wih_f;
    const float* bih = dir ? bih_b : bih_f;
    const float* Whh = dir ? Whh_b : Whh_f;
    const float* bhh = dir ? bhh_b : bhh_f;

    // per-lane q-pair constants (units u0+2p+k), NEGATED exp2-prescaled
    f32x2 gW2v[2], gb2v[2], fcv[2];
    f32x2 wxrv[2], wmrv[2], wxzv[2], wmzv[2], wxnv[2], wmnv[2];
    f32x2 brv[2], bzv[2], binv[2], bhnv[2];
#pragma unroll
    for (int p = 0; p < 2; ++p) {
#pragma unroll
        for (int k = 0; k < 2; ++k) {
            const int uq = u0 + 2 * p + k;
            gW2v[p][k] = gW[uq] * -L2E; gb2v[p][k] = gb[uq] * -L2E;
            fcv[p][k]  = fcW[uq];
            wxrv[p][k] = Wih[2 * uq] * -L2E;                wmrv[p][k] = Wih[2 * uq + 1] * -L2E;
            wxzv[p][k] = Wih[2 * (64 + uq)] * -L2E;         wmzv[p][k] = Wih[2 * (64 + uq) + 1] * -L2E;
            wxnv[p][k] = Wih[2 * (128 + uq)] * -2.0f * L2E; wmnv[p][k] = Wih[2 * (128 + uq) + 1] * -2.0f * L2E;
            brv[p][k]  = (bih[uq] + bhh[uq]) * -L2E;
            bzv[p][k]  = (bih[64 + uq] + bhh[64 + uq]) * -L2E;
            binv[p][k] = bih[128 + uq] * -2.0f * L2E;
            bhnv[p][k] = bhh[128 + uq] * -2.0f * L2E;
        }
    }
    const float rb0 = rb[0];

    // weight A-fragments: WfH = bf16(H) of NEG-prescaled Whh r/z/n rows +
    // natural rW (single level everywhere).
    Frag WfH[4][2];
#pragma unroll
    for (int t = 0; t < 4; ++t) {
        const float* src = (t < 3) ? (Whh + (t * 64 + u) * 64) : rW;
        const float sc = (t == 2) ? (-2.0f * L2E) : ((t == 3) ? 1.0f : -L2E);
#pragma unroll
        for (int kt = 0; kt < 2; ++kt) {
#pragma unroll
            for (int e = 0; e < 8; ++e) {
                const float v = src[kt * 32 + g * 8 + e] * sc;
                WfH[t][kt].s[e] = f2bf(v);
            }
        }
    }

    const float* inp = input + (size_t)b0 * 3072;
    float* impOut = out + 2048 + (size_t)dir * IMPN + (size_t)b0 * NT;

    // swizzled LDS offsets (constant per lane)
    const int jx   = j & 7;
    const int wOff = j * 64 + (((2 * w + (g >> 1)) ^ jx) << 3) + ((g & 1) << 2); // write, ushorts
    const int rOff0 = j * 64 + ((g ^ jx) << 3);          // read kt=0 block (g)
    const int rOff1 = j * 64 + (((4 + g) ^ jx) << 3);    // read kt=1 block (4+g)

    f32x2 h2[2] = {{0.0f, 0.0f}, {0.0f, 0.0f}};   // units u0..u0+3 as q-pairs (post-decay)
    float4 xmd;                                    // current step x,m,d

    for (int t = 0; t < NT; ++t) {
        const int tm = t & 31;
        if (tm == 0) {                            // 32-step chunk boundary
            __syncthreads();
            const int s = tid >> 4, tmi = tid & 15;
            if (t > 0) {                          // coalesced imp flush (2/thread)
                impOut[s * NT + (t - 32) + tmi]      = impbuf[s][tmi];
                impOut[s * NT + (t - 32) + tmi + 16] = impbuf[s][tmi + 16];
            }
            {                                     // stage x/m/d chunk (scan order)
                const float* base = inp + (size_t)s * 3072;
#pragma unroll
                for (int hh = 0; hh < 2; ++hh) {
                    const int tau = tmi + hh * 16;
                    const int tt = dir ? (NT - 1 - t - tau) : (t + tau);
                    float x = base[tt];
                    x = (x != x) ? -1.0f : x;
                    const float m  = base[2 * NT + tt];
                    const float dd = base[3 * NT + tt];
                    float4 v; v.x = x; v.y = m; v.z = dd; v.w = 0.0f;
                    *(float4*)&xmd_l[s][tau][0] = v;
                }
            }
            __syncthreads();
            xmd = *(const float4*)&xmd_l[j][0][0];
            // explicit decay at boundary (fused dsg was stale at tm==31)
            const f32x2 dz = {xmd.z, xmd.z};
#pragma unroll
            for (int p = 0; p < 2; ++p)
                h2[p] *= fsig2v(dz * gW2v[p] + gb2v[p]);
        }
        const int buf = t & 1;

        // ---- phase A: pack H + publish (decay already applied) ----
        const unsigned pH0 = cvt_pk_bf16(h2[0].x, h2[0].y);
        const unsigned pH1 = cvt_pk_bf16(h2[1].x, h2[1].y);
        {
            uint2 vH; vH.x = pH0; vH.y = pH1;
            *(uint2*)&h_lds[buf][wOff] = vH;      // swizzled, b64, <=2-way
        }
        __syncthreads();

        // ---- phase B: h B-frags (2x ds_read_b128, conflict-free) + 8 MFMA;
        //      then MFMA-independent precomputes in the MFMA shadow ----
        Frag A[2];
        A[0].v = *(const short8v*)&h_lds[buf][rOff0];
        A[1].v = *(const short8v*)&h_lds[buf][rOff1];
        const float4 xmd_nxt = *(const float4*)&xmd_l[j][(tm + 1) & 31][0];

        f32x4 acc0 = {0,0,0,0}, acc1 = {0,0,0,0}, acc2 = {0,0,0,0}, acc3 = {0,0,0,0};
#pragma unroll
        for (int kt = 0; kt < 2; ++kt) {
            acc3 = __builtin_amdgcn_mfma_f32_16x16x32_bf16(WfH[3][kt].v, A[kt].v, acc3, 0, 0, 0);
            acc0 = __builtin_amdgcn_mfma_f32_16x16x32_bf16(WfH[0][kt].v, A[kt].v, acc0, 0, 0, 0);
            acc2 = __builtin_amdgcn_mfma_f32_16x16x32_bf16(WfH[2][kt].v, A[kt].v, acc2, 0, 0, 0);
            acc1 = __builtin_amdgcn_mfma_f32_16x16x32_bf16(WfH[1][kt].v, A[kt].v, acc1, 0, 0, 0);
        }

        const float mv  = xmd.y;
        const float xcA = mv * xmd.x;             // m*x
        const float xcB = 1.0f - mv;
        const f32x2 xcA2 = {xcA, xcA}, xcB2 = {xcB, xcB}, mv2 = {mv, mv};
        f32x2 Cr[2], Qr[2], Cz[2], Qz[2], Cn[2], Qn[2], dsg[2];
#pragma unroll
        for (int p = 0; p < 2; ++p) {
            Cr[p] = wxrv[p] * xcA2 + wmrv[p] * mv2 + brv[p];
            Qr[p] = wxrv[p] * xcB2;
            Cz[p] = wxzv[p] * xcA2 + wmzv[p] * mv2 + bzv[p];
            Qz[p] = wxzv[p] * xcB2;
            Cn[p] = wxnv[p] * xcA2 + wmnv[p] * mv2 + binv[p];
            Qn[p] = wxnv[p] * xcB2;
        }
        if (tm != 31) {                           // next-step decay (fused)
            const f32x2 dzn = {xmd_nxt.z, xmd_nxt.z};
#pragma unroll
            for (int p = 0; p < 2; ++p)
                dsg[p] = fsig2v(dzn * gW2v[p] + gb2v[p]);
        } else {
            dsg[0] = (f32x2){1.0f, 1.0f};
            dsg[1] = (f32x2){1.0f, 1.0f};
        }

        // ---- phase C: short post-MFMA tail ----
        const float xh = acc3[0] + rb0;           // all acc3 rows identical (bcast A)
        if (w == 0 && g == 0) impbuf[j][tm] = xh;
        const f32x2 xh2 = {xh, xh};
#pragma unroll
        for (int p = 0; p < 2; ++p) {
            const f32x2 a0 = (p == 0) ? (f32x2){acc0[0], acc0[1]} : (f32x2){acc0[2], acc0[3]};
            const f32x2 a1 = (p == 0) ? (f32x2){acc1[0], acc1[1]} : (f32x2){acc1[2], acc1[3]};
            const f32x2 a2 = (p == 0) ? (f32x2){acc2[0], acc2[1]} : (f32x2){acc2[2], acc2[3]};
            const f32x2 rr = fsig2v((a0 + Cr[p]) + Qr[p] * xh2);
            const f32x2 zz = fsig2v((a1 + Cz[p]) + Qz[p] * xh2);
            const f32x2 an = Cn[p] + Qn[p] * xh2;           // indep of rr
            const f32x2 bn = a2 + bhnv[p];                  // indep of rr
            const f32x2 sn = fsig2v(rr * bn + an);
            const f32x2 nn = (f32x2){2.0f, 2.0f} * sn + (f32x2){-1.0f, -1.0f};
            h2[p] = (nn + zz * (h2[p] - nn)) * dsg[p];      // update + fused decay
        }
        xmd = xmd_nxt;
    }

    // epilogue: flush last imp chunk + fc reduction
    // (t=511 had tm==31 -> dsg=1, h2 is the raw final hidden state)
    __syncthreads();
    {
        const int fs = tid >> 4, ft = tid & 15;
        impOut[fs * NT + (NT - 32) + ft]      = impbuf[fs][ft];
        impOut[fs * NT + (NT - 32) + ft + 16] = impbuf[fs][ft + 16];
    }
    float pfc = h2[0].x * fcv[0].x + h2[0].y * fcv[0].y
              + h2[1].x * fcv[1].x + h2[1].y * fcv[1].y;
    pfc += __shfl_xor(pfc, 16);
    pfc += __shfl_xor(pfc, 32);
    if (lane < 16) fcpart[j][w] = pfc;
    __syncthreads();
    if (tid < 16) {
        float4 xp = *(const float4*)&fcpart[tid][0];
        ws[dir * 2048 + b0 + tid] = xp.x + xp.y + xp.z + xp.w + fcb[0];
    }
}

__global__ void brits_combine(const float* __restrict__ ws, float* __restrict__ out)
{
    int i = blockIdx.x * 256 + threadIdx.x;
    if (i < 2048) out[i] = 0.5f * (ws[i] + ws[2048 + i]);
}

extern "C" void kernel_launch(void* const* d_in, const int* in_sizes, int n_in,
                              void* d_out, int out_size, void* d_ws, size_t ws_size,
                              hipStream_t stream)
{
    const float* p[21];
    for (int i = 0; i < 21; ++i) p[i] = (const float*)d_in[i];
    float* out = (float*)d_out;
    float* ws  = (float*)d_ws;   // 4096 floats used

    brits_mfma<<<256, 256, 0, stream>>>(
        p[0],
        p[1], p[2], p[3], p[4], p[5], p[6], p[7], p[8], p[9], p[10],
        p[11], p[12], p[13], p[14], p[15], p[16], p[17], p[18], p[19], p[20],
        out, ws);
    brits_combine<<<8, 256, 0, stream>>>(ws, out);
}

// Round 17
// 220.579 us; speedup vs baseline: 1.2215x; 1.2215x over previous
//
#include <hip/hip_runtime.h>

#define NT   512
#define IMPN (2048 * 512)

typedef __attribute__((ext_vector_type(8))) short short8v;
typedef __attribute__((ext_vector_type(4))) float f32x4;
typedef __attribute__((ext_vector_type(2))) float f32x2;

union Frag { short8v v; unsigned short s[8]; };

#define L2E 1.4426950408889634f

// bare v_exp_f32 (2^x): 1 instruction (libm exp2f costs ~10+ VALU, R10).
__device__ __forceinline__ float fexp2(float x) {
    float r;
    asm("v_exp_f32 %0, %1" : "=v"(r) : "v"(x));
    return r;
}
__device__ __forceinline__ unsigned short f2bf(float f) {
    unsigned u = __float_as_uint(f);
    unsigned r = u + 0x7FFFu + ((u >> 16) & 1u);
    return (unsigned short)(r >> 16);
}
__device__ __forceinline__ float bf2f(unsigned short s) {
    return __uint_as_float(((unsigned)s) << 16);
}
__device__ __forceinline__ unsigned cvt_pk_bf16(float a, float b) {
    unsigned r;
    asm("v_cvt_pk_bf16_f32 %0, %1, %2" : "=v"(r) : "v"(a), "v"(b));
    return r;
}
__device__ __forceinline__ f32x2 exp2v(f32x2 a) {
    f32x2 e; e.x = fexp2(a.x); e.y = fexp2(a.y); return e;
}
__device__ __forceinline__ f32x2 rcpv(f32x2 a) {
    f32x2 r;
    r.x = __builtin_amdgcn_rcpf(a.x);
    r.y = __builtin_amdgcn_rcpf(a.y);
    return r;
}
// packed sigmoid: rcp(1 + exp2(arg)) per component
__device__ __forceinline__ f32x2 fsig2v(f32x2 arg) {
    f32x2 e = exp2v(arg);
    e += (f32x2){1.0f, 1.0f};
    return rcpv(e);
}

// 256 blocks x 256 threads, 1 block/CU (1024 full-lane waves = 1 wave/SIMD
// chip-wide; R6/R8: multi-stream variants waste lanes or idle CUs; R9: serial
// cross-lane latency > MFMA issue cost; R10/R11: bare v_exp_f32 only;
// R12: single-level h; R13/R16: at 1 wave/SIMD there are NO free issue slots —
// never add/move work to "hide" latency; only REMOVING issued ops wins;
// R14: f32x2 q-pair packing; R15: XOR-swizzled h_lds).
// Blocks 0..127 fwd, 128..255 bwd; block = 16 seqs. TRANSPOSED MFMA
// (weights = A, h = B): D[gate-row][seq], lane (j,g) owns seq j, units
// 16w+4g+{0..3}. 8 MFMA/step: r,z,n = W_H*h_H (6) + xh = rW_H*h_H (2).
// R17: RCP-MERGE — z-gate, n-gate, and next-step decay share ONE rcp:
//   h' = [e_z(1-e_n) + h(1+e_n)] / [(1+e_n)(1+e_z)(1+e_d_next)]
// (exact algebra of (n + z(h-n))*sigma_d; n=(1-e_n)/(1+e_n), z=1/(1+e_z)).
// 24 trans/step instead of 32. Top-of-step decay is folded into the previous
// update's denominator; chunk-boundary steps (stale xmd_nxt) mask e_d to 0
// and apply explicit decay after staging. Overflow-safe: |args| << 128.
// NEGATED exp2 PRESCALING: r/z x(-log2e), n x(-2log2e), decay x(-log2e);
// rW/acc3 natural. dir=1 consumes time REVERSED; imp stored at scan index.
__global__ __launch_bounds__(256, 1) void brits_mfma(
    const float* __restrict__ input,
    const float* __restrict__ gW_f, const float* __restrict__ gb_f,
    const float* __restrict__ rW_f, const float* __restrict__ rb_f,
    const float* __restrict__ fcW_f, const float* __restrict__ fcb_f,
    const float* __restrict__ Wih_f, const float* __restrict__ bih_f,
    const float* __restrict__ Whh_f, const float* __restrict__ bhh_f,
    const float* __restrict__ gW_b, const float* __restrict__ gb_b,
    const float* __restrict__ rW_b, const float* __restrict__ rb_b,
    const float* __restrict__ fcW_b, const float* __restrict__ fcb_b,
    const float* __restrict__ Wih_b, const float* __restrict__ bih_b,
    const float* __restrict__ Whh_b, const float* __restrict__ bhh_b,
    float* __restrict__ out, float* __restrict__ ws)
{
    __shared__ __align__(16) unsigned short h_lds[2][16 * 64];   // [buf][seq*64+swz-unit]
    __shared__ __align__(16) float xmd_l[16][33][4];             // [seq][tau(+pad)][x,m,d,-]
    __shared__ __align__(16) float impbuf[16][33];
    __shared__ __align__(16) float fcpart[16][4];

    const int tid  = threadIdx.x;
    const int w    = tid >> 6;
    const int lane = tid & 63;
    const int j    = lane & 15;          // seq owned by this lane
    const int g    = lane >> 4;
    const int u    = w * 16 + j;         // weight-frag row unit
    const int u0   = w * 16 + 4 * g;     // first of this lane's 4 gate units
    const int dir  = blockIdx.x >> 7;
    const int b0   = (blockIdx.x & 127) * 16;

    const float* gW  = dir ? gW_b  : gW_f;
    const float* gb  = dir ? gb_b  : gb_f;
    const float* rW  = dir ? rW_b  : rW_f;
    const float* rb  = dir ? rb_b  : rb_f;
    const float* fcW = dir ? fcW_b : fcW_f;
    const float* fcb = dir ? fcb_b : fcb_f;
    const float* Wih = dir ? Wih_b : Wih_f;
    const float* bih = dir ? bih_b : bih_f;
    const float* Whh = dir ? Whh_b : Whh_f;
    const float* bhh = dir ? bhh_b : bhh_f;

    // per-lane q-pair constants (units u0+2p+k), NEGATED exp2-prescaled
    f32x2 gW2v[2], gb2v[2], fcv[2];
    f32x2 wxrv[2], wmrv[2], wxzv[2], wmzv[2], wxnv[2], wmnv[2];
    f32x2 brv[2], bzv[2], binv[2], bhnv[2];
#pragma unroll
    for (int p = 0; p < 2; ++p) {
#pragma unroll
        for (int k = 0; k < 2; ++k) {
            const int uq = u0 + 2 * p + k;
            gW2v[p][k] = gW[uq] * -L2E; gb2v[p][k] = gb[uq] * -L2E;
            fcv[p][k]  = fcW[uq];
            wxrv[p][k] = Wih[2 * uq] * -L2E;                wmrv[p][k] = Wih[2 * uq + 1] * -L2E;
            wxzv[p][k] = Wih[2 * (64 + uq)] * -L2E;         wmzv[p][k] = Wih[2 * (64 + uq) + 1] * -L2E;
            wxnv[p][k] = Wih[2 * (128 + uq)] * -2.0f * L2E; wmnv[p][k] = Wih[2 * (128 + uq) + 1] * -2.0f * L2E;
            brv[p][k]  = (bih[uq] + bhh[uq]) * -L2E;
            bzv[p][k]  = (bih[64 + uq] + bhh[64 + uq]) * -L2E;
            binv[p][k] = bih[128 + uq] * -2.0f * L2E;
            bhnv[p][k] = bhh[128 + uq] * -2.0f * L2E;
        }
    }
    const float rb0 = rb[0];

    // weight A-fragments: WfH = bf16(H) of NEG-prescaled Whh r/z/n rows +
    // natural rW (single level everywhere).
    Frag WfH[4][2];
#pragma unroll
    for (int t = 0; t < 4; ++t) {
        const float* src = (t < 3) ? (Whh + (t * 64 + u) * 64) : rW;
        const float sc = (t == 2) ? (-2.0f * L2E) : ((t == 3) ? 1.0f : -L2E);
#pragma unroll
        for (int kt = 0; kt < 2; ++kt) {
#pragma unroll
            for (int e = 0; e < 8; ++e) {
                const float v = src[kt * 32 + g * 8 + e] * sc;
                WfH[t][kt].s[e] = f2bf(v);
            }
        }
    }

    const float* inp = input + (size_t)b0 * 3072;
    float* impOut = out + 2048 + (size_t)dir * IMPN + (size_t)b0 * NT;

    // swizzled LDS offsets (constant per lane)
    const int jx   = j & 7;
    const int wOff = j * 64 + (((2 * w + (g >> 1)) ^ jx) << 3) + ((g & 1) << 2); // write, ushorts
    const int rOff0 = j * 64 + ((g ^ jx) << 3);          // read kt=0 block (g)
    const int rOff1 = j * 64 + (((4 + g) ^ jx) << 3);    // read kt=1 block (4+g)

    f32x2 h2[2] = {{0.0f, 0.0f}, {0.0f, 0.0f}};   // units u0..u0+3 as q-pairs (post-decay)
    float4 xmd;                                    // current step x,m,d

    for (int t = 0; t < NT; ++t) {
        const int tm = t & 31;
        if (tm == 0) {                            // 32-step chunk boundary
            __syncthreads();
            const int s = tid >> 4, tmi = tid & 15;
            if (t > 0) {                          // coalesced imp flush (2/thread)
                impOut[s * NT + (t - 32) + tmi]      = impbuf[s][tmi];
                impOut[s * NT + (t - 32) + tmi + 16] = impbuf[s][tmi + 16];
            }
            {                                     // stage x/m/d chunk (scan order)
                const float* base = inp + (size_t)s * 3072;
#pragma unroll
                for (int hh = 0; hh < 2; ++hh) {
                    const int tau = tmi + hh * 16;
                    const int tt = dir ? (NT - 1 - t - tau) : (t + tau);
                    float x = base[tt];
                    x = (x != x) ? -1.0f : x;
                    const float m  = base[2 * NT + tt];
                    const float dd = base[3 * NT + tt];
                    float4 v; v.x = x; v.y = m; v.z = dd; v.w = 0.0f;
                    *(float4*)&xmd_l[s][tau][0] = v;
                }
            }
            __syncthreads();
            xmd = *(const float4*)&xmd_l[j][0][0];
            // explicit decay at boundary (fused e_d was masked at tm==31)
            const f32x2 dz = {xmd.z, xmd.z};
#pragma unroll
            for (int p = 0; p < 2; ++p)
                h2[p] *= fsig2v(dz * gW2v[p] + gb2v[p]);
        }
        const int buf = t & 1;

        // ---- phase A: pack H + publish (decay already applied) ----
        const unsigned pH0 = cvt_pk_bf16(h2[0].x, h2[0].y);
        const unsigned pH1 = cvt_pk_bf16(h2[1].x, h2[1].y);
        {
            uint2 vH; vH.x = pH0; vH.y = pH1;
            *(uint2*)&h_lds[buf][wOff] = vH;      // swizzled, b64, <=2-way
        }
        __syncthreads();

        // ---- phase B: h B-frags (2x ds_read_b128, conflict-free) + 8 MFMA ----
        Frag A[2];
        A[0].v = *(const short8v*)&h_lds[buf][rOff0];
        A[1].v = *(const short8v*)&h_lds[buf][rOff1];
        const float4 xmd_nxt = *(const float4*)&xmd_l[j][(tm + 1) & 31][0];

        f32x4 acc0 = {0,0,0,0}, acc1 = {0,0,0,0}, acc2 = {0,0,0,0}, acc3 = {0,0,0,0};
#pragma unroll
        for (int kt = 0; kt < 2; ++kt) {
            acc3 = __builtin_amdgcn_mfma_f32_16x16x32_bf16(WfH[3][kt].v, A[kt].v, acc3, 0, 0, 0);
            acc0 = __builtin_amdgcn_mfma_f32_16x16x32_bf16(WfH[0][kt].v, A[kt].v, acc0, 0, 0, 0);
            acc2 = __builtin_amdgcn_mfma_f32_16x16x32_bf16(WfH[2][kt].v, A[kt].v, acc2, 0, 0, 0);
            acc1 = __builtin_amdgcn_mfma_f32_16x16x32_bf16(WfH[1][kt].v, A[kt].v, acc1, 0, 0, 0);
        }

        // ---- phase C: gates with merged rcp (z + n + next-decay in one) ----
        const float xh = acc3[0] + rb0;           // all acc3 rows identical (bcast A)
        if (w == 0 && g == 0) impbuf[j][tm] = xh;
        const float mv = xmd.y;
        const float xc = mv * xmd.x + (1.0f - mv) * xh;
        const f32x2 xc2 = {xc, xc};
        const f32x2 mv2 = {mv, mv};
        const float dmask = (tm != 31) ? 1.0f : 0.0f;      // mask stale e_d
        const f32x2 dzn = {xmd_nxt.z * dmask, xmd_nxt.z * dmask};
        const f32x2 dmv = {dmask, dmask};
        const f32x2 one2 = {1.0f, 1.0f};
#pragma unroll
        for (int p = 0; p < 2; ++p) {
            const f32x2 a0 = (p == 0) ? (f32x2){acc0[0], acc0[1]} : (f32x2){acc0[2], acc0[3]};
            const f32x2 a1 = (p == 0) ? (f32x2){acc1[0], acc1[1]} : (f32x2){acc1[2], acc1[3]};
            const f32x2 a2 = (p == 0) ? (f32x2){acc2[0], acc2[1]} : (f32x2){acc2[2], acc2[3]};
            // r-gate: classic sigmoid (its rcp can't merge — feeds n's arg)
            const f32x2 rr = fsig2v(a0 + wxrv[p] * xc2 + wmrv[p] * mv2 + brv[p]);
            const f32x2 az = a1 + wxzv[p] * xc2 + wmzv[p] * mv2 + bzv[p];
            const f32x2 an = wxnv[p] * xc2 + wmnv[p] * mv2 + binv[p];   // indep of rr
            const f32x2 bn = a2 + bhnv[p];                              // indep of rr
            const f32x2 e_z = exp2v(az);
            const f32x2 e_n = exp2v(rr * bn + an);
            const f32x2 e_d = exp2v(dzn * gW2v[p] + gb2v[p] * dmv) * dmv; // masked: ->0
            const f32x2 t1   = one2 + e_n;
            const f32x2 onem = one2 - e_n;
            const f32x2 N = onem * e_z + h2[p] * t1;   // e_z(1-e_n) + h(1+e_n)
            const f32x2 D = t1 * (one2 + e_z) * (one2 + e_d);
            h2[p] = N * rcpv(D);                       // update + z + next-decay
        }
        xmd = xmd_nxt;
    }

    // epilogue: flush last imp chunk + fc reduction
    // (t=511 had tm==31 -> e_d masked, h2 is the raw final hidden state)
    __syncthreads();
    {
        const int fs = tid >> 4, ft = tid & 15;
        impOut[fs * NT + (NT - 32) + ft]      = impbuf[fs][ft];
        impOut[fs * NT + (NT - 32) + ft + 16] = impbuf[fs][ft + 16];
    }
    float pfc = h2[0].x * fcv[0].x + h2[0].y * fcv[0].y
              + h2[1].x * fcv[1].x + h2[1].y * fcv[1].y;
    pfc += __shfl_xor(pfc, 16);
    pfc += __shfl_xor(pfc, 32);
    if (lane < 16) fcpart[j][w] = pfc;
    __syncthreads();
    if (tid < 16) {
        float4 xp = *(const float4*)&fcpart[tid][0];
        ws[dir * 2048 + b0 + tid] = xp.x + xp.y + xp.z + xp.w + fcb[0];
    }
}

__global__ void brits_combine(const float* __restrict__ ws, float* __restrict__ out)
{
    int i = blockIdx.x * 256 + threadIdx.x;
    if (i < 2048) out[i] = 0.5f * (ws[i] + ws[2048 + i]);
}

extern "C" void kernel_launch(void* const* d_in, const int* in_sizes, int n_in,
                              void* d_out, int out_size, void* d_ws, size_t ws_size,
                              hipStream_t stream)
{
    const float* p[21];
    for (int i = 0; i < 21; ++i) p[i] = (const float*)d_in[i];
    float* out = (float*)d_out;
    float* ws  = (float*)d_ws;   // 4096 floats used

    brits_mfma<<<256, 256, 0, stream>>>(
        p[0],
        p[1], p[2], p[3], p[4], p[5], p[6], p[7], p[8], p[9], p[10],
        p[11], p[12], p[13], p[14], p[15], p[16], p[17], p[18], p[19], p[20],
        out, ws);
    brits_combine<<<8, 256, 0, stream>>>(ws, out);
}